// Round 8
// baseline (128.957 us; speedup 1.0000x reference)
//
#include <hip/hip_runtime.h>

#define NN 8192
#define INF 128
#define OUTF 64
#define EMB 32
#define L2E 1.4426950408889634f

// workspace offsets (bytes)
#define OFF_HJ    0u          // f32 hJ[8192][64]                     : 2097152
#define OFF_META  2097152u    // float4 meta[8192] = (es, ed, U, W)   : 131072
#define OFF_PQRAW 2228224u    // float2 PQraw[8192] = (e^ed, e^.2ed)  : 65536
#define OFF_RKE   2293760u    // int rankE[8192] (rank of es_i)       : 32768
#define OFF_RKD   2326528u    // int rankD[8192] (rank of ed_j)       : 32768
#define OFF_JSRT  2359296u    // int jsort[8192] (ed-sorted -> j)     : 32768
#define OFF_TI    2392064u    // int ti[8192] = #{j: ed_j < -es_i}    : 32768
#define OFF_PQS   2424832u    // float2 PQs[8192] = (P/S, Q/S)        : 65536
#define OFF_PREA  2490368u    // f32 PreA[8192][64] seg-local excl.   : 2097152
#define OFF_PREB  4587520u    // f32 PreB[8192][64]                   : 2097152
#define OFF_SEGA  6684672u    // f32 segA[64][64] segment totals      : 16384
#define OFF_SEGB  6701056u    // f32 segB[64][64]                     : 16384

// ---- D1: h = input@W; meta=(es,ed,U,W); PQraw; hJ rows; zero ranks ----
__global__ __launch_bounds__(256) void d1_h(
    const float* __restrict__ input, const float* __restrict__ Wm,
    const float* __restrict__ av, const float* __restrict__ embeds,
    const float* __restrict__ intw, const float* __restrict__ betap,
    float* __restrict__ hJ, float4* __restrict__ meta,
    float2* __restrict__ PQraw, int* __restrict__ rankE,
    int* __restrict__ rankD)
{
    const int t    = threadIdx.x;
    const int wid  = t >> 6;
    const int lane = t & 63;
    const int blk  = blockIdx.x;
    const int i0 = blk * 16 + wid * 4;

    if (t < 16) rankE[blk * 16 + t] = 0;
    else if (t < 32) rankD[blk * 16 + (t - 16)] = 0;

    const float a1 = av[lane];
    const float a2 = av[64 + lane];
    const float* x0 = input + (size_t)i0 * INF;

    float acc0 = 0.f, acc1 = 0.f, acc2 = 0.f, acc3 = 0.f;
#pragma unroll 4
    for (int k = 0; k < INF; k += 4) {
        const float wk0 = Wm[(k + 0) * OUTF + lane];
        const float wk1 = Wm[(k + 1) * OUTF + lane];
        const float wk2 = Wm[(k + 2) * OUTF + lane];
        const float wk3 = Wm[(k + 3) * OUTF + lane];
        const float4 xa = *(const float4*)(x0 + k);
        const float4 xb = *(const float4*)(x0 + INF + k);
        const float4 xc = *(const float4*)(x0 + 2 * INF + k);
        const float4 xd = *(const float4*)(x0 + 3 * INF + k);
        acc0 = fmaf(xa.x, wk0, acc0); acc0 = fmaf(xa.y, wk1, acc0);
        acc0 = fmaf(xa.z, wk2, acc0); acc0 = fmaf(xa.w, wk3, acc0);
        acc1 = fmaf(xb.x, wk0, acc1); acc1 = fmaf(xb.y, wk1, acc1);
        acc1 = fmaf(xb.z, wk2, acc1); acc1 = fmaf(xb.w, wk3, acc1);
        acc2 = fmaf(xc.x, wk0, acc2); acc2 = fmaf(xc.y, wk1, acc2);
        acc2 = fmaf(xc.z, wk2, acc2); acc2 = fmaf(xc.w, wk3, acc2);
        acc3 = fmaf(xd.x, wk0, acc3); acc3 = fmaf(xd.y, wk1, acc3);
        acc3 = fmaf(xd.z, wk2, acc3); acc3 = fmaf(xd.w, wk3, acc3);
    }

    // h rows, coalesced f32
    hJ[(size_t)(i0 + 0) * OUTF + lane] = acc0;
    hJ[(size_t)(i0 + 1) * OUTF + lane] = acc1;
    hJ[(size_t)(i0 + 2) * OUTF + lane] = acc2;
    hJ[(size_t)(i0 + 3) * OUTF + lane] = acc3;

    float accs[4] = {acc0, acc1, acc2, acc3};
#pragma unroll
    for (int r = 0; r < 4; ++r) {
        float v1 = accs[r] * a1;   // -> es_i
        float v2 = accs[r] * a2;   // -> ed_i
#pragma unroll
        for (int o = 32; o > 0; o >>= 1) {
            v1 += __shfl_xor(v1, o);
            v2 += __shfl_xor(v2, o);
        }
        float p = 0.f;
        if (lane < EMB) p = embeds[(size_t)(i0 + r) * EMB + lane] * intw[lane];
#pragma unroll
        for (int o = 16; o > 0; o >>= 1) p += __shfl_xor(p, o);

        if (lane == 0) {
            const float q = betap[0] * p;     // beta * ii_i
            const float es = v1, ed = v2;
            meta[i0 + r] = make_float4(
                es, ed,
                __builtin_amdgcn_exp2f((es + q) * L2E),          // U_i
                __builtin_amdgcn_exp2f((0.2f * es + q) * L2E));  // W_i
            PQraw[i0 + r] = make_float2(
                __builtin_amdgcn_exp2f(ed * L2E),                // P_j
                __builtin_amdgcn_exp2f(0.2f * ed * L2E));        // Q_j
        }
    }
}

// ---- D2: exact lexicographic ranks of es and ed (the only O(N^2) pass) ----
__global__ __launch_bounds__(256) void d2_rank(
    const float4* __restrict__ meta, int* __restrict__ rankE,
    int* __restrict__ rankD)
{
    __shared__ float cE[1024];
    __shared__ float cD[1024];
    const int t = threadIdx.x;
    const int i = blockIdx.x * 256 + t;
    const int cb = blockIdx.y * 1024;
    for (int k = t; k < 1024; k += 256) {
        const float4 m = meta[cb + k];
        cE[k] = m.x; cD[k] = m.y;
    }
    __syncthreads();
    const float4 mi = meta[i];
    const float ei = mi.x, edi = mi.y;
    int ce = 0, cd = 0;
    for (int k = 0; k < 1024; k += 4) {
        const float4 e4 = *(const float4*)&cE[k];
        const float4 d4 = *(const float4*)&cD[k];
        const int b = cb + k;
        ce += (e4.x < ei) || (e4.x == ei && b + 0 < i);
        ce += (e4.y < ei) || (e4.y == ei && b + 1 < i);
        ce += (e4.z < ei) || (e4.z == ei && b + 2 < i);
        ce += (e4.w < ei) || (e4.w == ei && b + 3 < i);
        cd += (d4.x < edi) || (d4.x == edi && b + 0 < i);
        cd += (d4.y < edi) || (d4.y == edi && b + 1 < i);
        cd += (d4.z < edi) || (d4.z == edi && b + 2 < i);
        cd += (d4.w < edi) || (d4.w == edi && b + 3 < i);
    }
    atomicAdd(&rankE[i], ce);
    atomicAdd(&rankD[i], cd);
}

// ---- D3 (1 block): scatter to sorted order; scalar scans; S_j; PQs; t_i ----
__global__ __launch_bounds__(256) void d3_scan(
    const float4* __restrict__ meta, const float2* __restrict__ PQraw,
    const int* __restrict__ rankE, const int* __restrict__ rankD,
    int* __restrict__ jsort, int* __restrict__ ti, float2* __restrict__ PQs)
{
    __shared__ float esS[NN];   // es sorted ascending
    __shared__ float edS[NN];   // ed sorted ascending
    __shared__ float scU[NN];   // U in es-order -> exclusive prefix
    __shared__ float scW[NN];   // W in es-order -> exclusive prefix
    __shared__ float pU[256], pW[256];
    const int t = threadIdx.x;

    for (int i = t; i < NN; i += 256) {
        const float4 m = meta[i];
        const int re = rankE[i], rd = rankD[i];
        esS[re] = m.x; scU[re] = m.z; scW[re] = m.w;
        edS[rd] = m.y; jsort[rd] = i;
    }
    __syncthreads();

    // chunk sums (32 per thread)
    const int c0 = t * 32;
    float su = 0.f, sw = 0.f;
    for (int k = 0; k < 32; ++k) { su += scU[c0 + k]; sw += scW[c0 + k]; }
    pU[t] = su; pW[t] = sw;
    __syncthreads();
    // inclusive Hillis-Steele scan of 256 partials
    for (int off = 1; off < 256; off <<= 1) {
        const float au = (t >= off) ? pU[t - off] : 0.f;
        const float aw = (t >= off) ? pW[t - off] : 0.f;
        __syncthreads();
        pU[t] += au; pW[t] += aw;
        __syncthreads();
    }
    const float offU = pU[t] - su, offW = pW[t] - sw;   // exclusive chunk offsets
    const float tu = pU[255], tw = pW[255];             // totals
    __syncthreads();
    // in-place exclusive prefix within chunk
    float ru = offU, rw = offW;
    for (int k = 0; k < 32; ++k) {
        const float a = scU[c0 + k], b = scW[c0 + k];
        scU[c0 + k] = ru; scW[c0 + k] = rw;
        ru += a; rw += b;
    }
    __syncthreads();

    // per column j: cnt = #{es_i < -ed_j}; S_j; normalized (P', Q')
    for (int j = t; j < NN; j += 256) {
        const float th = -meta[j].y;
        const float2 pq = PQraw[j];
        int lo = 0;
#pragma unroll
        for (int s = NN / 2; s; s >>= 1)
            if (esS[lo + s - 1] < th) lo += s;
        const float preU = (lo < NN) ? scU[lo] : tu;
        const float preW = (lo < NN) ? scW[lo] : tw;
        const float S = pq.x * (tu - preU) + pq.y * preW;
        const float inv = 1.0f / S;
        PQs[j] = make_float2(pq.x * inv, pq.y * inv);
    }
    // per row i: t_i = #{ed_j < -es_i}
    for (int i = t; i < NN; i += 256) {
        const float th = -meta[i].x;
        int lo = 0;
#pragma unroll
        for (int s = NN / 2; s; s >>= 1)
            if (edS[lo + s - 1] < th) lo += s;
        ti[i] = lo;
    }
}

// ---- D4: vector prefix sums (64 segments of 128) of P'h, Q'h in ed-order ----
__global__ __launch_bounds__(256) void d4_scanvec(
    const int* __restrict__ jsort, const float2* __restrict__ PQs,
    const float* __restrict__ hJ, float* __restrict__ PreA,
    float* __restrict__ PreB, float* __restrict__ segA,
    float* __restrict__ segB)
{
    __shared__ float wtA[4][64], wtB[4][64];
    const int t = threadIdx.x, w = t >> 6, lane = t & 63;
    const int cb = blockIdx.x * 128 + w * 32;

    float aA = 0.f, aB = 0.f;
    for (int cc = 0; cc < 32; ++cc) {
        const int j = jsort[cb + cc];
        const float2 pq = PQs[j];
        const float hv = hJ[(size_t)j * OUTF + lane];
        aA = fmaf(pq.x, hv, aA);
        aB = fmaf(pq.y, hv, aB);
    }
    wtA[w][lane] = aA; wtB[w][lane] = aB;
    __syncthreads();
    float oA = 0.f, oB = 0.f;
#pragma unroll
    for (int ww = 0; ww < 3; ++ww)
        if (ww < w) { oA += wtA[ww][lane]; oB += wtB[ww][lane]; }

    aA = oA; aB = oB;
    for (int cc = 0; cc < 32; ++cc) {
        const int c = cb + cc;
        const int j = jsort[c];
        const float2 pq = PQs[j];
        const float hv = hJ[(size_t)j * OUTF + lane];
        PreA[(size_t)c * OUTF + lane] = aA;
        PreB[(size_t)c * OUTF + lane] = aB;
        aA = fmaf(pq.x, hv, aA);
        aB = fmaf(pq.y, hv, aB);
    }
    if (w == 3) {
        segA[blockIdx.x * 64 + lane] = aA;   // segment total
        segB[blockIdx.x * 64 + lane] = aB;
    }
}

// ---- D5: h'[i] = U_i*SufA(t_i) + W_i*PreB(t_i); ELU; store ----
__global__ __launch_bounds__(256) void d5_out(
    const float4* __restrict__ meta, const int* __restrict__ ti,
    const float* __restrict__ PreA, const float* __restrict__ PreB,
    const float* __restrict__ segA, const float* __restrict__ segB,
    float* __restrict__ out)
{
    __shared__ float sA[65][64], sB[65][64];
    const int t = threadIdx.x, w = t >> 6, lane = t & 63;

    if (w == 0) {
        float run = 0.f;
        for (int s = 0; s < 64; ++s) { sA[s][lane] = run; run += segA[s * 64 + lane]; }
        sA[64][lane] = run;
    } else if (w == 1) {
        float run = 0.f;
        for (int s = 0; s < 64; ++s) { sB[s][lane] = run; run += segB[s * 64 + lane]; }
        sB[64][lane] = run;
    }
    __syncthreads();

    const int base = blockIdx.x * 32 + w * 8;
    for (int rr = 0; rr < 8; ++rr) {
        const int i = base + rr;
        const float4 m = meta[i];
        const int tt = ti[i];
        const float totA = sA[64][lane];
        float pA, pB;
        if (tt < NN) {
            const int sg = tt >> 7;
            pA = sA[sg][lane] + PreA[(size_t)tt * OUTF + lane];
            pB = sB[sg][lane] + PreB[(size_t)tt * OUTF + lane];
        } else {
            pA = totA;
            pB = sB[64][lane];
        }
        const float v = m.z * (totA - pA) + m.w * pB;
        out[(size_t)i * OUTF + lane] =
            v > 0.f ? v : (__builtin_amdgcn_exp2f(v * L2E) - 1.f);
    }
}

extern "C" void kernel_launch(void* const* d_in, const int* in_sizes, int n_in,
                              void* d_out, int out_size, void* d_ws, size_t ws_size,
                              hipStream_t stream)
{
    const float* input  = (const float*)d_in[0];
    // d_in[1] = adj : unused by the reference computation
    const float* embeds = (const float*)d_in[2];
    const float* Wm     = (const float*)d_in[3];
    const float* av     = (const float*)d_in[4];
    const float* intw   = (const float*)d_in[5];
    // d_in[6] = intent_b : cancels in column softmax
    const float* betap  = (const float*)d_in[7];
    float* out = (float*)d_out;

    char* ws = (char*)d_ws;
    float*  hJ    = (float*)(ws + OFF_HJ);
    float4* meta  = (float4*)(ws + OFF_META);
    float2* PQraw = (float2*)(ws + OFF_PQRAW);
    int*    rankE = (int*)(ws + OFF_RKE);
    int*    rankD = (int*)(ws + OFF_RKD);
    int*    jsort = (int*)(ws + OFF_JSRT);
    int*    tiB   = (int*)(ws + OFF_TI);
    float2* PQs   = (float2*)(ws + OFF_PQS);
    float*  PreA  = (float*)(ws + OFF_PREA);
    float*  PreB  = (float*)(ws + OFF_PREB);
    float*  segA  = (float*)(ws + OFF_SEGA);
    float*  segB  = (float*)(ws + OFF_SEGB);

    d1_h<<<NN / 16, 256, 0, stream>>>(input, Wm, av, embeds, intw, betap,
                                      hJ, meta, PQraw, rankE, rankD);
    d2_rank<<<dim3(32, 8), 256, 0, stream>>>(meta, rankE, rankD);
    d3_scan<<<1, 256, 0, stream>>>(meta, PQraw, rankE, rankD, jsort, tiB, PQs);
    d4_scanvec<<<64, 256, 0, stream>>>(jsort, PQs, hJ, PreA, PreB, segA, segB);
    d5_out<<<256, 256, 0, stream>>>(meta, tiB, PreA, PreB, segA, segB, out);
}

// Round 9
// 117.164 us; speedup vs baseline: 1.1007x; 1.1007x over previous
//
#include <hip/hip_runtime.h>

#define NN 8192
#define INF 128
#define OUTF 64
#define EMB 32
#define L2E 1.4426950408889634f

// workspace offsets (bytes)
#define OFF_HJ    0u          // f32 hJ[8192][64]                     : 2097152
#define OFF_META  2097152u    // float4 meta[8192] = (es, ed, U, W)   : 131072
#define OFF_PQRAW 2228224u    // float2 PQraw[8192] = (e^ed, e^.2ed)  : 65536
#define OFF_ESS   2293760u    // f32 esS[8192]  es sorted asc         : 32768
#define OFF_UWS   2326528u    // float2 UWs[8192] (U,W) in es-order   : 65536
#define OFF_EDS   2392064u    // f32 edS[8192]  ed sorted asc         : 32768
#define OFF_JSRT  2424832u    // int jsort[8192] ed-order -> j        : 32768
#define OFF_PREA  2457600u    // f32 PreA[8192][64] seg-local excl    : 2097152
#define OFF_PREB  4554752u    // f32 PreB[8192][64]                   : 2097152
#define OFF_SEGA  6651904u    // f32 segA[64][64] segment totals      : 16384
#define OFF_SEGB  6668288u    // f32 segB[64][64]                     : 16384

// ---- D1: h = input@W; hJ rows; meta=(es,ed,U,W); PQraw ----
__global__ __launch_bounds__(256) void d1_h(
    const float* __restrict__ input, const float* __restrict__ Wm,
    const float* __restrict__ av, const float* __restrict__ embeds,
    const float* __restrict__ intw, const float* __restrict__ betap,
    float* __restrict__ hJ, float4* __restrict__ meta,
    float2* __restrict__ PQraw)
{
    const int t    = threadIdx.x;
    const int wid  = t >> 6;
    const int lane = t & 63;
    const int i0 = blockIdx.x * 16 + wid * 4;

    const float a1 = av[lane];
    const float a2 = av[64 + lane];
    const float* x0 = input + (size_t)i0 * INF;

    float acc0 = 0.f, acc1 = 0.f, acc2 = 0.f, acc3 = 0.f;
#pragma unroll 4
    for (int k = 0; k < INF; k += 4) {
        const float wk0 = Wm[(k + 0) * OUTF + lane];
        const float wk1 = Wm[(k + 1) * OUTF + lane];
        const float wk2 = Wm[(k + 2) * OUTF + lane];
        const float wk3 = Wm[(k + 3) * OUTF + lane];
        const float4 xa = *(const float4*)(x0 + k);
        const float4 xb = *(const float4*)(x0 + INF + k);
        const float4 xc = *(const float4*)(x0 + 2 * INF + k);
        const float4 xd = *(const float4*)(x0 + 3 * INF + k);
        acc0 = fmaf(xa.x, wk0, acc0); acc0 = fmaf(xa.y, wk1, acc0);
        acc0 = fmaf(xa.z, wk2, acc0); acc0 = fmaf(xa.w, wk3, acc0);
        acc1 = fmaf(xb.x, wk0, acc1); acc1 = fmaf(xb.y, wk1, acc1);
        acc1 = fmaf(xb.z, wk2, acc1); acc1 = fmaf(xb.w, wk3, acc1);
        acc2 = fmaf(xc.x, wk0, acc2); acc2 = fmaf(xc.y, wk1, acc2);
        acc2 = fmaf(xc.z, wk2, acc2); acc2 = fmaf(xc.w, wk3, acc2);
        acc3 = fmaf(xd.x, wk0, acc3); acc3 = fmaf(xd.y, wk1, acc3);
        acc3 = fmaf(xd.z, wk2, acc3); acc3 = fmaf(xd.w, wk3, acc3);
    }

    hJ[(size_t)(i0 + 0) * OUTF + lane] = acc0;
    hJ[(size_t)(i0 + 1) * OUTF + lane] = acc1;
    hJ[(size_t)(i0 + 2) * OUTF + lane] = acc2;
    hJ[(size_t)(i0 + 3) * OUTF + lane] = acc3;

    float accs[4] = {acc0, acc1, acc2, acc3};
#pragma unroll
    for (int r = 0; r < 4; ++r) {
        float v1 = accs[r] * a1;   // -> es_i
        float v2 = accs[r] * a2;   // -> ed_i
#pragma unroll
        for (int o = 32; o > 0; o >>= 1) {
            v1 += __shfl_xor(v1, o);
            v2 += __shfl_xor(v2, o);
        }
        float p = 0.f;
        if (lane < EMB) p = embeds[(size_t)(i0 + r) * EMB + lane] * intw[lane];
#pragma unroll
        for (int o = 16; o > 0; o >>= 1) p += __shfl_xor(p, o);

        if (lane == 0) {
            const float q = betap[0] * p;     // beta * ii_i
            const float es = v1, ed = v2;
            meta[i0 + r] = make_float4(
                es, ed,
                __builtin_amdgcn_exp2f((es + q) * L2E),          // U_i
                __builtin_amdgcn_exp2f((0.2f * es + q) * L2E));  // W_i
            PQraw[i0 + r] = make_float2(
                __builtin_amdgcn_exp2f(ed * L2E),                // P_j
                __builtin_amdgcn_exp2f(0.2f * ed * L2E));        // Q_j
        }
    }
}

// ---- D2: exact ranks (block-local, full scan in LDS) + direct scatter ----
__global__ __launch_bounds__(256) void d2_rank(
    const float4* __restrict__ meta, float* __restrict__ esS,
    float2* __restrict__ UWs, float* __restrict__ edS,
    int* __restrict__ jsort)
{
    __shared__ float2 ee[NN];   // 64 KB: (es, ed) for all rows
    const int t = threadIdx.x;
    for (int k = t; k < NN; k += 256) {
        const float4 m = meta[k];
        ee[k] = make_float2(m.x, m.y);
    }
    __syncthreads();

    const int il = t >> 4;               // 16 rows per block
    const int s  = t & 15;               // 16 segments of 512 per row
    const int i  = blockIdx.x * 16 + il;
    const float2 mi = ee[i];

    int ce = 0, cd = 0;
    const int j0 = s * (NN / 16);
    for (int it = 0; it < NN / 16; ++it) {
        const int k = j0 + ((s + it) & (NN / 16 - 1));   // bank-spread rotation
        const float2 v = ee[k];
        ce += (v.x < mi.x) || (v.x == mi.x && k < i);
        cd += (v.y < mi.y) || (v.y == mi.y && k < i);
    }
#pragma unroll
    for (int off = 8; off; off >>= 1) {
        ce += __shfl_down(ce, off);
        cd += __shfl_down(cd, off);
    }
    if (s == 0) {   // exact lexicographic rank -> bijective scatter
        const float4 m = meta[i];
        esS[ce] = m.x;
        UWs[ce] = make_float2(m.z, m.w);
        edS[cd] = m.y;
        jsort[cd] = i;
    }
}

// ---- D3: per-block redundant scan of (U,W); per-col S_j; seg vector scan ----
__global__ __launch_bounds__(256, 1) void d3_seg(
    const float* __restrict__ esS, const float2* __restrict__ UWs,
    const float* __restrict__ edS, const int* __restrict__ jsort,
    const float2* __restrict__ PQraw, const float* __restrict__ hJ,
    float* __restrict__ PreA, float* __restrict__ PreB,
    float* __restrict__ segA, float* __restrict__ segB)
{
    __shared__ float  esL[NN];      // 32 KB
    __shared__ float2 uwL[NN];      // 64 KB -> exclusive prefix in-place
    __shared__ float  pU[256], pW[256];
    __shared__ float2 pqsL[128];
    __shared__ float  wtA[4][64], wtB[4][64];

    const int t = threadIdx.x;
    for (int k = t; k < NN; k += 256) {
        esL[k] = esS[k];
        uwL[k] = UWs[k];
    }
    __syncthreads();

    // in-block scan of U,W (es-order): chunk sums -> HS scan -> writeback
    const int c0 = t * 32;
    float su = 0.f, sw = 0.f;
    for (int k = 0; k < 32; ++k) { su += uwL[c0 + k].x; sw += uwL[c0 + k].y; }
    pU[t] = su; pW[t] = sw;
    __syncthreads();
    for (int off = 1; off < 256; off <<= 1) {
        const float au = (t >= off) ? pU[t - off] : 0.f;
        const float aw = (t >= off) ? pW[t - off] : 0.f;
        __syncthreads();
        pU[t] += au; pW[t] += aw;
        __syncthreads();
    }
    float ru = pU[t] - su, rw = pW[t] - sw;
    for (int k = 0; k < 32; ++k) {
        const float2 a = uwL[c0 + k];
        uwL[c0 + k] = make_float2(ru, rw);
        ru += a.x; rw += a.y;
    }
    __syncthreads();
    const float tu = pU[255], tw = pW[255];

    // per-column: binary search + normalization (128 cols per block)
    if (t < 128) {
        const int c = blockIdx.x * 128 + t;
        const float th = -edS[c];           // coalesced: edS sorted = col order
        int lo = 0;
#pragma unroll
        for (int s2 = NN / 2; s2; s2 >>= 1)
            if (esL[lo + s2 - 1] < th) lo += s2;
        const float preU = (lo < NN) ? uwL[lo].x : tu;
        const float preW = (lo < NN) ? uwL[lo].y : tw;
        const float2 pq = PQraw[jsort[c]];
        const float S = pq.x * (tu - preU) + pq.y * preW;
        const float inv = 1.0f / S;
        pqsL[t] = make_float2(pq.x * inv, pq.y * inv);
    }
    __syncthreads();

    // segmented vector scan (segment = this block's 128 cols; 4 waves x 32)
    const int w = t >> 6, lane = t & 63;
    const int cb = blockIdx.x * 128 + w * 32;

    float aA = 0.f, aB = 0.f;
    for (int cc = 0; cc < 32; ++cc) {
        const int j = jsort[cb + cc];
        const float2 pq = pqsL[w * 32 + cc];
        const float hv = hJ[(size_t)j * OUTF + lane];
        aA = fmaf(pq.x, hv, aA);
        aB = fmaf(pq.y, hv, aB);
    }
    wtA[w][lane] = aA; wtB[w][lane] = aB;
    __syncthreads();
    float oA = 0.f, oB = 0.f;
#pragma unroll
    for (int ww = 0; ww < 3; ++ww)
        if (ww < w) { oA += wtA[ww][lane]; oB += wtB[ww][lane]; }

    aA = oA; aB = oB;
    for (int cc = 0; cc < 32; ++cc) {
        const int c = cb + cc;
        const int j = jsort[c];
        const float2 pq = pqsL[w * 32 + cc];
        const float hv = hJ[(size_t)j * OUTF + lane];
        PreA[(size_t)c * OUTF + lane] = aA;
        PreB[(size_t)c * OUTF + lane] = aB;
        aA = fmaf(pq.x, hv, aA);
        aB = fmaf(pq.y, hv, aB);
    }
    if (w == 3) {
        segA[blockIdx.x * 64 + lane] = aA;   // segment totals
        segB[blockIdx.x * 64 + lane] = aB;
    }
}

// ---- D4: per-row binsearch + two-level combine + ELU + store ----
__global__ __launch_bounds__(256) void d4_out(
    const float4* __restrict__ meta, const float* __restrict__ edS,
    const float* __restrict__ PreA, const float* __restrict__ PreB,
    const float* __restrict__ segA, const float* __restrict__ segB,
    float* __restrict__ out)
{
    __shared__ float edL[NN];               // 32 KB
    __shared__ float sA[65][64], sB[65][64];
    __shared__ int   tis[32];

    const int t = threadIdx.x, w = t >> 6, lane = t & 63;
    for (int k = t; k < NN; k += 256) edL[k] = edS[k];
    if (w == 0) {
        float run = 0.f;
        for (int s = 0; s < 64; ++s) { sA[s][lane] = run; run += segA[s * 64 + lane]; }
        sA[64][lane] = run;
    } else if (w == 1) {
        float run = 0.f;
        for (int s = 0; s < 64; ++s) { sB[s][lane] = run; run += segB[s * 64 + lane]; }
        sB[64][lane] = run;
    }
    __syncthreads();

    if (t < 32) {   // 32 parallel row binsearches: t_i = #{ed_j < -es_i}
        const float th = -meta[blockIdx.x * 32 + t].x;
        int lo = 0;
#pragma unroll
        for (int s2 = NN / 2; s2; s2 >>= 1)
            if (edL[lo + s2 - 1] < th) lo += s2;
        tis[t] = lo;
    }
    __syncthreads();

    const int base = blockIdx.x * 32 + w * 8;
    for (int rr = 0; rr < 8; ++rr) {
        const int i = base + rr;
        const float4 m = meta[i];
        const int tt = tis[w * 8 + rr];
        const float totA = sA[64][lane];
        float pA, pB;
        if (tt < NN) {
            const int sg = tt >> 7;
            pA = sA[sg][lane] + PreA[(size_t)tt * OUTF + lane];
            pB = sB[sg][lane] + PreB[(size_t)tt * OUTF + lane];
        } else {
            pA = totA;
            pB = sB[64][lane];
        }
        const float v = m.z * (totA - pA) + m.w * pB;
        out[(size_t)i * OUTF + lane] =
            v > 0.f ? v : (__builtin_amdgcn_exp2f(v * L2E) - 1.f);
    }
}

extern "C" void kernel_launch(void* const* d_in, const int* in_sizes, int n_in,
                              void* d_out, int out_size, void* d_ws, size_t ws_size,
                              hipStream_t stream)
{
    const float* input  = (const float*)d_in[0];
    // d_in[1] = adj : unused by the reference computation
    const float* embeds = (const float*)d_in[2];
    const float* Wm     = (const float*)d_in[3];
    const float* av     = (const float*)d_in[4];
    const float* intw   = (const float*)d_in[5];
    // d_in[6] = intent_b : cancels in column softmax
    const float* betap  = (const float*)d_in[7];
    float* out = (float*)d_out;

    char* ws = (char*)d_ws;
    float*  hJ    = (float*)(ws + OFF_HJ);
    float4* meta  = (float4*)(ws + OFF_META);
    float2* PQraw = (float2*)(ws + OFF_PQRAW);
    float*  esS   = (float*)(ws + OFF_ESS);
    float2* UWs   = (float2*)(ws + OFF_UWS);
    float*  edS   = (float*)(ws + OFF_EDS);
    int*    jsort = (int*)(ws + OFF_JSRT);
    float*  PreA  = (float*)(ws + OFF_PREA);
    float*  PreB  = (float*)(ws + OFF_PREB);
    float*  segA  = (float*)(ws + OFF_SEGA);
    float*  segB  = (float*)(ws + OFF_SEGB);

    d1_h<<<NN / 16, 256, 0, stream>>>(input, Wm, av, embeds, intw, betap,
                                      hJ, meta, PQraw);
    d2_rank<<<NN / 16, 256, 0, stream>>>(meta, esS, UWs, edS, jsort);
    d3_seg<<<64, 256, 0, stream>>>(esS, UWs, edS, jsort, PQraw, hJ,
                                   PreA, PreB, segA, segB);
    d4_out<<<NN / 32, 256, 0, stream>>>(meta, edS, PreA, PreB, segA, segB, out);
}

// Round 10
// 97.695 us; speedup vs baseline: 1.3200x; 1.1993x over previous
//
#include <hip/hip_runtime.h>
#include <hip/hip_bf16.h>

#define NN 8192
#define INF 128
#define OUTF 64
#define EMB 32
#define LOG2E 1.4426950408889634f
#define ISPLIT 64
#define ICH (NN / ISPLIT)
#define MGUARD 64.0f

typedef __attribute__((ext_vector_type(8))) short bf16x8;
typedef __attribute__((ext_vector_type(4))) float f32x4;

// workspace offsets (bytes)
#define OFF_HB   0u          // bf16 hB[4][256][64][8] fragment-ready : 1048576
#define OFF_UW   1048576u    // float2 UW[8192] = (2^u, 2^w)          : 65536
#define OFF_E12  1114112u    // float2 e12[8192] = (e1,e2)*log2e      : 65536
#define OFF_S    1179648u    // f32 S[8192] column sums (atomic)      : 32768
#define OFF_CNT  1212416u    // int cnt[64] per-M-tile arrival count  : 256

// hB element (nb,tile,l,e) = h[tile*32 + (l>>4)*8 + e][nb*16 + (l&15)]
// -> k4 B-fragment load for a wave = contiguous 1KB (64 lanes x 16B).

// ---- Kernel 1: h = input@W (16 rows/block) -> hB, UW, e12; zero S/out/cnt ----
__global__ __launch_bounds__(256) void k1_h(
    const float* __restrict__ input, const float* __restrict__ Wm,
    const float* __restrict__ av, const float* __restrict__ embeds,
    const float* __restrict__ intw, const float* __restrict__ betap,
    ushort* __restrict__ hB, float2* __restrict__ UW,
    float2* __restrict__ e12, float* __restrict__ S,
    float* __restrict__ out, int* __restrict__ cnt)
{
    __shared__ float hl[16][65];
    const int t    = threadIdx.x;
    const int wid  = t >> 6;
    const int lane = t & 63;
    const int blk  = blockIdx.x;
    const int i0 = blk * 16 + wid * 4;

    if (t < 16) S[blk * 16 + t] = 0.f;          // zero atomic S each call
    if (blk == 0 && t < 64) cnt[t] = 0;         // zero tile counters each call
    // zero this block's out slice (16 rows x 64) for atomic accumulation
    {
        const float4 z = make_float4(0.f, 0.f, 0.f, 0.f);
        *(float4*)(out + (size_t)blk * 1024 + t * 4) = z;
    }

    const float a1 = av[lane];
    const float a2 = av[64 + lane];
    const float* x0 = input + (size_t)i0 * INF;

    float acc0 = 0.f, acc1 = 0.f, acc2 = 0.f, acc3 = 0.f;
#pragma unroll 4
    for (int k = 0; k < INF; k += 4) {
        const float wk0 = Wm[(k + 0) * OUTF + lane];
        const float wk1 = Wm[(k + 1) * OUTF + lane];
        const float wk2 = Wm[(k + 2) * OUTF + lane];
        const float wk3 = Wm[(k + 3) * OUTF + lane];
        const float4 xa = *(const float4*)(x0 + k);
        const float4 xb = *(const float4*)(x0 + INF + k);
        const float4 xc = *(const float4*)(x0 + 2 * INF + k);
        const float4 xd = *(const float4*)(x0 + 3 * INF + k);
        acc0 = fmaf(xa.x, wk0, acc0); acc0 = fmaf(xa.y, wk1, acc0);
        acc0 = fmaf(xa.z, wk2, acc0); acc0 = fmaf(xa.w, wk3, acc0);
        acc1 = fmaf(xb.x, wk0, acc1); acc1 = fmaf(xb.y, wk1, acc1);
        acc1 = fmaf(xb.z, wk2, acc1); acc1 = fmaf(xb.w, wk3, acc1);
        acc2 = fmaf(xc.x, wk0, acc2); acc2 = fmaf(xc.y, wk1, acc2);
        acc2 = fmaf(xc.z, wk2, acc2); acc2 = fmaf(xc.w, wk3, acc2);
        acc3 = fmaf(xd.x, wk0, acc3); acc3 = fmaf(xd.y, wk1, acc3);
        acc3 = fmaf(xd.z, wk2, acc3); acc3 = fmaf(xd.w, wk3, acc3);
    }

    hl[wid * 4 + 0][lane] = acc0;
    hl[wid * 4 + 1][lane] = acc1;
    hl[wid * 4 + 2][lane] = acc2;
    hl[wid * 4 + 3][lane] = acc3;

    float accs[4] = {acc0, acc1, acc2, acc3};
#pragma unroll
    for (int r = 0; r < 4; ++r) {
        float v1 = accs[r] * a1;
        float v2 = accs[r] * a2;
#pragma unroll
        for (int o = 32; o > 0; o >>= 1) {
            v1 += __shfl_xor(v1, o);
            v2 += __shfl_xor(v2, o);
        }
        float p = 0.f;
        if (lane < EMB) p = embeds[(size_t)(i0 + r) * EMB + lane] * intw[lane];
#pragma unroll
        for (int o = 16; o > 0; o >>= 1) p += __shfl_xor(p, o);

        if (lane == 0) {
            const float q = betap[0] * p;
            UW[i0 + r] = make_float2(
                __builtin_amdgcn_exp2f((v1 + q) * LOG2E),
                __builtin_amdgcn_exp2f((0.2f * v1 + q) * LOG2E));
            e12[i0 + r] = make_float2(v2 * LOG2E, 0.2f * v2 * LOG2E);
        }
    }

    __syncthreads();
    // fragment-ready store: 128 threads x 16B (layout HW-verified R5/R6)
    if (t < 128) {
        const int rr = t >> 6;
        const int of = t & 63;
        const int nb = of >> 4;
        const int r2 = of & 15;
        const int tile = blk >> 1;
        const int g = (blk & 1) * 2 + rr;
        const int l = g * 16 + r2;
        union { bf16x8 v; ushort us[8]; } pk;
#pragma unroll
        for (int e = 0; e < 8; ++e) {
            __hip_bfloat16 b = __float2bfloat16(hl[rr * 8 + e][of]);
            pk.us[e] = *(ushort*)&b;
        }
        *(bf16x8*)(hB + (size_t)(((nb * 256 + tile) * 64 + l) * 8)) = pk.v;
    }
}

// ---- Kernel 2: partial column sums -> atomic S[j] (exp-free) ----
__global__ __launch_bounds__(256) void k2_colsum(
    const float2* __restrict__ UW, const float2* __restrict__ e12,
    float* __restrict__ S)
{
    const int j0 = blockIdx.x * 256 + threadIdx.x;   // [0,4096)
    const int j1 = j0 + 4096;
    const float2 ea = e12[j0];
    const float2 eb = e12[j1];
    const float Ma = fmaxf(ea.x, ea.y) + MGUARD;
    const float Mb = fmaxf(eb.x, eb.y) + MGUARD;
    const float Pa = __builtin_amdgcn_exp2f(ea.x - Ma);
    const float Qa = __builtin_amdgcn_exp2f(ea.y - Ma);
    const float Pb = __builtin_amdgcn_exp2f(eb.x - Mb);
    const float Qb = __builtin_amdgcn_exp2f(eb.y - Mb);

    const float* up = (const float*)UW + (size_t)blockIdx.y * ICH * 2;
    float sa = 0.f, sb = 0.f;
#pragma unroll 8
    for (int rr = 0; rr < ICH * 2; rr += 4) {
        const float4 c = *(const float4*)(up + rr);   // U0 W0 U1 W1
        sa += fmaxf(c.x * Pa, c.y * Qa);
        sa += fmaxf(c.z * Pa, c.w * Qa);
        sb += fmaxf(c.x * Pb, c.y * Qb);
        sb += fmaxf(c.z * Pb, c.w * Qb);
    }
    unsafeAtomicAdd(&S[j0], sa);
    unsafeAtomicAdd(&S[j1], sb);
}

// ---- Kernel 4: attn @ h partials -> atomicAdd out; last block does ELU ----
__global__ __launch_bounds__(256) void k4_mm(
    const float2* __restrict__ UW, const float2* __restrict__ e12,
    const float* __restrict__ S, const ushort* __restrict__ hB,
    float* __restrict__ out, int* __restrict__ cnt)
{
    __shared__ float2 pq[1024];   // normalized (P/S, Q/S) for this j-chunk
    __shared__ int isLast;

    const int wid  = threadIdx.x >> 6;
    const int lane = threadIdx.x & 63;
    const int r = lane & 15;
    const int g = lane >> 4;
    const int mt = blockIdx.x;              // 64 M-tiles of 128 rows
    const int jb = blockIdx.y * 1024;       // 8 j-chunks of 1024 cols

    // prologue: per-chunk normalized factors (same M expr as k2 -> exact cancel)
    for (int c = threadIdx.x; c < 1024; c += 256) {
        const float2 e = e12[jb + c];
        const float M = fmaxf(e.x, e.y) + MGUARD;
        const float inv = 1.0f / S[jb + c];
        pq[c] = make_float2(__builtin_amdgcn_exp2f(e.x - M) * inv,
                            __builtin_amdgcn_exp2f(e.y - M) * inv);
    }
    __syncthreads();

    const int ibase = mt * 128 + wid * 32;
    const float2 c0 = UW[ibase + r];
    const float2 c1 = UW[ibase + 16 + r];

    f32x4 a00 = {0,0,0,0}, a01 = {0,0,0,0}, a02 = {0,0,0,0}, a03 = {0,0,0,0};
    f32x4 a10 = {0,0,0,0}, a11 = {0,0,0,0}, a12 = {0,0,0,0}, a13 = {0,0,0,0};

    for (int j0 = jb; j0 < jb + 1024; j0 += 32) {
        const int jj = j0 + g * 8;
        const float* pqp = (const float*)&pq[jj - jb];
        const float4 q0 = *(const float4*)(pqp);       // P0 Q0 P1 Q1
        const float4 q1 = *(const float4*)(pqp + 4);
        const float4 q2 = *(const float4*)(pqp + 8);
        const float4 q3 = *(const float4*)(pqp + 12);

        float e00 = fmaxf(c0.x * q0.x, c0.y * q0.y);
        float e01 = fmaxf(c0.x * q0.z, c0.y * q0.w);
        float e02 = fmaxf(c0.x * q1.x, c0.y * q1.y);
        float e03 = fmaxf(c0.x * q1.z, c0.y * q1.w);
        float e04 = fmaxf(c0.x * q2.x, c0.y * q2.y);
        float e05 = fmaxf(c0.x * q2.z, c0.y * q2.w);
        float e06 = fmaxf(c0.x * q3.x, c0.y * q3.y);
        float e07 = fmaxf(c0.x * q3.z, c0.y * q3.w);

        float e10 = fmaxf(c1.x * q0.x, c1.y * q0.y);
        float e11 = fmaxf(c1.x * q0.z, c1.y * q0.w);
        float e12v= fmaxf(c1.x * q1.x, c1.y * q1.y);
        float e13 = fmaxf(c1.x * q1.z, c1.y * q1.w);
        float e14 = fmaxf(c1.x * q2.x, c1.y * q2.y);
        float e15 = fmaxf(c1.x * q2.z, c1.y * q2.w);
        float e16 = fmaxf(c1.x * q3.x, c1.y * q3.y);
        float e17 = fmaxf(c1.x * q3.z, c1.y * q3.w);

        union { bf16x8 v; unsigned u[4]; } A0, A1;
        asm("v_cvt_pk_bf16_f32 %0, %1, %2" : "=v"(A0.u[0]) : "v"(e00), "v"(e01));
        asm("v_cvt_pk_bf16_f32 %0, %1, %2" : "=v"(A0.u[1]) : "v"(e02), "v"(e03));
        asm("v_cvt_pk_bf16_f32 %0, %1, %2" : "=v"(A0.u[2]) : "v"(e04), "v"(e05));
        asm("v_cvt_pk_bf16_f32 %0, %1, %2" : "=v"(A0.u[3]) : "v"(e06), "v"(e07));
        asm("v_cvt_pk_bf16_f32 %0, %1, %2" : "=v"(A1.u[0]) : "v"(e10), "v"(e11));
        asm("v_cvt_pk_bf16_f32 %0, %1, %2" : "=v"(A1.u[1]) : "v"(e12v),"v"(e13));
        asm("v_cvt_pk_bf16_f32 %0, %1, %2" : "=v"(A1.u[2]) : "v"(e14), "v"(e15));
        asm("v_cvt_pk_bf16_f32 %0, %1, %2" : "=v"(A1.u[3]) : "v"(e16), "v"(e17));

        const int tile = j0 >> 5;
        const ushort* hb = hB + (size_t)(tile * 64 + lane) * 8;
        const bf16x8 b0 = *(const bf16x8*)(hb);
        const bf16x8 b1 = *(const bf16x8*)(hb + 256 * 64 * 8);
        const bf16x8 b2 = *(const bf16x8*)(hb + 2 * 256 * 64 * 8);
        const bf16x8 b3 = *(const bf16x8*)(hb + 3 * 256 * 64 * 8);

        a00 = __builtin_amdgcn_mfma_f32_16x16x32_bf16(A0.v, b0, a00, 0, 0, 0);
        a01 = __builtin_amdgcn_mfma_f32_16x16x32_bf16(A0.v, b1, a01, 0, 0, 0);
        a02 = __builtin_amdgcn_mfma_f32_16x16x32_bf16(A0.v, b2, a02, 0, 0, 0);
        a03 = __builtin_amdgcn_mfma_f32_16x16x32_bf16(A0.v, b3, a03, 0, 0, 0);
        a10 = __builtin_amdgcn_mfma_f32_16x16x32_bf16(A1.v, b0, a10, 0, 0, 0);
        a11 = __builtin_amdgcn_mfma_f32_16x16x32_bf16(A1.v, b1, a11, 0, 0, 0);
        a12 = __builtin_amdgcn_mfma_f32_16x16x32_bf16(A1.v, b2, a12, 0, 0, 0);
        a13 = __builtin_amdgcn_mfma_f32_16x16x32_bf16(A1.v, b3, a13, 0, 0, 0);
    }

    // accumulate partials into out (device-coherent f32 HW atomics)
#pragma unroll
    for (int m = 0; m < 4; ++m) {
        const int row0 = ibase + g * 4 + m;
        const int row1 = ibase + 16 + g * 4 + m;
        unsafeAtomicAdd(&out[(size_t)row0 * OUTF + 0  + r], a00[m]);
        unsafeAtomicAdd(&out[(size_t)row0 * OUTF + 16 + r], a01[m]);
        unsafeAtomicAdd(&out[(size_t)row0 * OUTF + 32 + r], a02[m]);
        unsafeAtomicAdd(&out[(size_t)row0 * OUTF + 48 + r], a03[m]);
        unsafeAtomicAdd(&out[(size_t)row1 * OUTF + 0  + r], a10[m]);
        unsafeAtomicAdd(&out[(size_t)row1 * OUTF + 16 + r], a11[m]);
        unsafeAtomicAdd(&out[(size_t)row1 * OUTF + 32 + r], a12[m]);
        unsafeAtomicAdd(&out[(size_t)row1 * OUTF + 48 + r], a13[m]);
    }

    // tail election: 8th arriver for this M-tile applies ELU (no spinning)
    __threadfence();
    __syncthreads();
    if (threadIdx.x == 0) {
        const int old = __hip_atomic_fetch_add(&cnt[mt], 1, __ATOMIC_ACQ_REL,
                                               __HIP_MEMORY_SCOPE_AGENT);
        isLast = (old == 7);
    }
    __syncthreads();
    if (isLast) {
        for (int k = threadIdx.x; k < 128 * OUTF; k += 256) {
            float* p = &out[(size_t)mt * 128 * OUTF + k];
            const float v = __hip_atomic_load(p, __ATOMIC_RELAXED,
                                              __HIP_MEMORY_SCOPE_AGENT);
            *p = v > 0.f ? v : (__builtin_amdgcn_exp2f(v * LOG2E) - 1.f);
        }
    }
}

extern "C" void kernel_launch(void* const* d_in, const int* in_sizes, int n_in,
                              void* d_out, int out_size, void* d_ws, size_t ws_size,
                              hipStream_t stream)
{
    const float* input  = (const float*)d_in[0];
    // d_in[1] = adj : unused by the reference computation
    const float* embeds = (const float*)d_in[2];
    const float* Wm     = (const float*)d_in[3];
    const float* av     = (const float*)d_in[4];
    const float* intw   = (const float*)d_in[5];
    // d_in[6] = intent_b : cancels in column softmax
    const float* betap  = (const float*)d_in[7];
    float* out = (float*)d_out;

    char* ws = (char*)d_ws;
    ushort* hB  = (ushort*)(ws + OFF_HB);
    float2* UW  = (float2*)(ws + OFF_UW);
    float2* e12 = (float2*)(ws + OFF_E12);
    float* S    = (float*)(ws + OFF_S);
    int*   cnt  = (int*)(ws + OFF_CNT);

    k1_h<<<NN / 16, 256, 0, stream>>>(input, Wm, av, embeds, intw, betap,
                                      hB, UW, e12, S, out, cnt);
    k2_colsum<<<dim3(NN / 512, ISPLIT), 256, 0, stream>>>(UW, e12, S);
    k4_mm<<<dim3(64, 8), 256, 0, stream>>>(UW, e12, S, hB, out, cnt);
}

// Round 11
// 57.062 us; speedup vs baseline: 2.2599x; 1.7121x over previous
//
#include <hip/hip_runtime.h>
#include <hip/hip_bf16.h>

#define NN 8192
#define INF 128
#define OUTF 64
#define EMB 32
#define LOG2E 1.4426950408889634f
#define ISPLIT 64
#define ICH (NN / ISPLIT)
#define MGUARD 64.0f

typedef __attribute__((ext_vector_type(8))) short bf16x8;
typedef __attribute__((ext_vector_type(4))) float f32x4;

// workspace offsets (bytes)
#define OFF_HB   0u          // bf16 hB[4][256][64][8] fragment-ready : 1048576
#define OFF_UW   1048576u    // float2 UW[8192] = (2^u, 2^w)          : 65536
#define OFF_E12  1114112u    // float2 e12[8192] = (e1,e2)*log2e      : 65536
#define OFF_S    1179648u    // f32 S[8192] column sums (atomic)      : 32768
#define OFF_PART 1212416u    // f32 part[JS][8192][64]

// hB element (nb,tile,l,e) = h[tile*32 + (l>>4)*8 + e][nb*16 + (l&15)]
// -> k4 B-fragment load for a wave = contiguous 1KB (64 lanes x 16B).

// ---- Kernel 1: h = input@W (16 rows/block) -> hB, UW, e12; zero S ----
__global__ __launch_bounds__(256) void k1_h(
    const float* __restrict__ input, const float* __restrict__ Wm,
    const float* __restrict__ av, const float* __restrict__ embeds,
    const float* __restrict__ intw, const float* __restrict__ betap,
    ushort* __restrict__ hB, float2* __restrict__ UW,
    float2* __restrict__ e12, float* __restrict__ S)
{
    __shared__ float hl[16][65];
    const int t    = threadIdx.x;
    const int wid  = t >> 6;
    const int lane = t & 63;
    const int blk  = blockIdx.x;
    const int i0 = blk * 16 + wid * 4;

    if (t < 16) S[blk * 16 + t] = 0.f;   // zero atomic accumulator each call

    const float a1 = av[lane];
    const float a2 = av[64 + lane];
    const float* x0 = input + (size_t)i0 * INF;

    float acc0 = 0.f, acc1 = 0.f, acc2 = 0.f, acc3 = 0.f;
#pragma unroll 4
    for (int k = 0; k < INF; k += 4) {
        const float wk0 = Wm[(k + 0) * OUTF + lane];
        const float wk1 = Wm[(k + 1) * OUTF + lane];
        const float wk2 = Wm[(k + 2) * OUTF + lane];
        const float wk3 = Wm[(k + 3) * OUTF + lane];
        const float4 xa = *(const float4*)(x0 + k);
        const float4 xb = *(const float4*)(x0 + INF + k);
        const float4 xc = *(const float4*)(x0 + 2 * INF + k);
        const float4 xd = *(const float4*)(x0 + 3 * INF + k);
        acc0 = fmaf(xa.x, wk0, acc0); acc0 = fmaf(xa.y, wk1, acc0);
        acc0 = fmaf(xa.z, wk2, acc0); acc0 = fmaf(xa.w, wk3, acc0);
        acc1 = fmaf(xb.x, wk0, acc1); acc1 = fmaf(xb.y, wk1, acc1);
        acc1 = fmaf(xb.z, wk2, acc1); acc1 = fmaf(xb.w, wk3, acc1);
        acc2 = fmaf(xc.x, wk0, acc2); acc2 = fmaf(xc.y, wk1, acc2);
        acc2 = fmaf(xc.z, wk2, acc2); acc2 = fmaf(xc.w, wk3, acc2);
        acc3 = fmaf(xd.x, wk0, acc3); acc3 = fmaf(xd.y, wk1, acc3);
        acc3 = fmaf(xd.z, wk2, acc3); acc3 = fmaf(xd.w, wk3, acc3);
    }

    hl[wid * 4 + 0][lane] = acc0;
    hl[wid * 4 + 1][lane] = acc1;
    hl[wid * 4 + 2][lane] = acc2;
    hl[wid * 4 + 3][lane] = acc3;

    float accs[4] = {acc0, acc1, acc2, acc3};
#pragma unroll
    for (int r = 0; r < 4; ++r) {
        float v1 = accs[r] * a1;
        float v2 = accs[r] * a2;
#pragma unroll
        for (int o = 32; o > 0; o >>= 1) {
            v1 += __shfl_xor(v1, o);
            v2 += __shfl_xor(v2, o);
        }
        float p = 0.f;
        if (lane < EMB) p = embeds[(size_t)(i0 + r) * EMB + lane] * intw[lane];
#pragma unroll
        for (int o = 16; o > 0; o >>= 1) p += __shfl_xor(p, o);

        if (lane == 0) {
            const float q = betap[0] * p;
            UW[i0 + r] = make_float2(
                __builtin_amdgcn_exp2f((v1 + q) * LOG2E),
                __builtin_amdgcn_exp2f((0.2f * v1 + q) * LOG2E));
            e12[i0 + r] = make_float2(v2 * LOG2E, 0.2f * v2 * LOG2E);
        }
    }

    __syncthreads();
    // fragment-ready store: 128 threads x 16B (layout HW-verified R5/R6)
    if (t < 128) {
        const int rr = t >> 6;
        const int of = t & 63;
        const int nb = of >> 4;
        const int r2 = of & 15;
        const int tile = blk >> 1;
        const int g = (blk & 1) * 2 + rr;
        const int l = g * 16 + r2;
        union { bf16x8 v; ushort us[8]; } pk;
#pragma unroll
        for (int e = 0; e < 8; ++e) {
            __hip_bfloat16 b = __float2bfloat16(hl[rr * 8 + e][of]);
            pk.us[e] = *(ushort*)&b;
        }
        *(bf16x8*)(hB + (size_t)(((nb * 256 + tile) * 64 + l) * 8)) = pk.v;
    }
}

// ---- Kernel 2: partial column sums -> atomic S[j] (exp-free) ----
__global__ __launch_bounds__(256) void k2_colsum(
    const float2* __restrict__ UW, const float2* __restrict__ e12,
    float* __restrict__ S)
{
    const int j0 = blockIdx.x * 256 + threadIdx.x;   // [0,4096)
    const int j1 = j0 + 4096;
    const float2 ea = e12[j0];
    const float2 eb = e12[j1];
    const float Ma = fmaxf(ea.x, ea.y) + MGUARD;
    const float Mb = fmaxf(eb.x, eb.y) + MGUARD;
    const float Pa = __builtin_amdgcn_exp2f(ea.x - Ma);
    const float Qa = __builtin_amdgcn_exp2f(ea.y - Ma);
    const float Pb = __builtin_amdgcn_exp2f(eb.x - Mb);
    const float Qb = __builtin_amdgcn_exp2f(eb.y - Mb);

    const float* up = (const float*)UW + (size_t)blockIdx.y * ICH * 2;
    float sa = 0.f, sb = 0.f;
#pragma unroll 8
    for (int rr = 0; rr < ICH * 2; rr += 4) {
        const float4 c = *(const float4*)(up + rr);   // U0 W0 U1 W1
        sa += fmaxf(c.x * Pa, c.y * Qa);
        sa += fmaxf(c.z * Pa, c.w * Qa);
        sb += fmaxf(c.x * Pb, c.y * Qb);
        sb += fmaxf(c.z * Pb, c.w * Qb);
    }
    unsafeAtomicAdd(&S[j0], sa);
    unsafeAtomicAdd(&S[j1], sb);
}

// ---- Kernel 4: h_prime partial = attention @ h (MFMA bf16, LDS pq prologue) ----
__global__ __launch_bounds__(256) void k4_mm(
    const float2* __restrict__ UW, const float2* __restrict__ e12,
    const float* __restrict__ S, const ushort* __restrict__ hB,
    float* __restrict__ part, int jch)
{
    __shared__ float2 pq[2048];   // normalized (P/S, Q/S) for this j-chunk

    const int wid  = threadIdx.x >> 6;
    const int lane = threadIdx.x & 63;
    const int r = lane & 15;
    const int g = lane >> 4;
    const int ibase = blockIdx.x * 128 + wid * 32;
    const int jb = blockIdx.y * jch;

    // prologue: per-chunk normalized factors (same M expr as k2 -> exact cancel)
    for (int c = threadIdx.x; c < jch; c += 256) {
        const float2 e = e12[jb + c];
        const float M = fmaxf(e.x, e.y) + MGUARD;
        const float inv = 1.0f / S[jb + c];
        pq[c] = make_float2(__builtin_amdgcn_exp2f(e.x - M) * inv,
                            __builtin_amdgcn_exp2f(e.y - M) * inv);
    }
    __syncthreads();

    const float2 c0 = UW[ibase + r];        // (U,W) for A-frag0 row
    const float2 c1 = UW[ibase + 16 + r];   // (U,W) for A-frag1 row

    f32x4 a00 = {0,0,0,0}, a01 = {0,0,0,0}, a02 = {0,0,0,0}, a03 = {0,0,0,0};
    f32x4 a10 = {0,0,0,0}, a11 = {0,0,0,0}, a12 = {0,0,0,0}, a13 = {0,0,0,0};

    for (int j0 = jb; j0 < jb + jch; j0 += 32) {
        const int jj = j0 + g * 8;
        const float* pqp = (const float*)&pq[jj - jb];
        const float4 q0 = *(const float4*)(pqp);       // P0 Q0 P1 Q1
        const float4 q1 = *(const float4*)(pqp + 4);
        const float4 q2 = *(const float4*)(pqp + 8);
        const float4 q3 = *(const float4*)(pqp + 12);

        float e00 = fmaxf(c0.x * q0.x, c0.y * q0.y);
        float e01 = fmaxf(c0.x * q0.z, c0.y * q0.w);
        float e02 = fmaxf(c0.x * q1.x, c0.y * q1.y);
        float e03 = fmaxf(c0.x * q1.z, c0.y * q1.w);
        float e04 = fmaxf(c0.x * q2.x, c0.y * q2.y);
        float e05 = fmaxf(c0.x * q2.z, c0.y * q2.w);
        float e06 = fmaxf(c0.x * q3.x, c0.y * q3.y);
        float e07 = fmaxf(c0.x * q3.z, c0.y * q3.w);

        float e10 = fmaxf(c1.x * q0.x, c1.y * q0.y);
        float e11 = fmaxf(c1.x * q0.z, c1.y * q0.w);
        float e12v= fmaxf(c1.x * q1.x, c1.y * q1.y);
        float e13 = fmaxf(c1.x * q1.z, c1.y * q1.w);
        float e14 = fmaxf(c1.x * q2.x, c1.y * q2.y);
        float e15 = fmaxf(c1.x * q2.z, c1.y * q2.w);
        float e16 = fmaxf(c1.x * q3.x, c1.y * q3.y);
        float e17 = fmaxf(c1.x * q3.z, c1.y * q3.w);

        union { bf16x8 v; unsigned u[4]; } A0, A1;
        asm("v_cvt_pk_bf16_f32 %0, %1, %2" : "=v"(A0.u[0]) : "v"(e00), "v"(e01));
        asm("v_cvt_pk_bf16_f32 %0, %1, %2" : "=v"(A0.u[1]) : "v"(e02), "v"(e03));
        asm("v_cvt_pk_bf16_f32 %0, %1, %2" : "=v"(A0.u[2]) : "v"(e04), "v"(e05));
        asm("v_cvt_pk_bf16_f32 %0, %1, %2" : "=v"(A0.u[3]) : "v"(e06), "v"(e07));
        asm("v_cvt_pk_bf16_f32 %0, %1, %2" : "=v"(A1.u[0]) : "v"(e10), "v"(e11));
        asm("v_cvt_pk_bf16_f32 %0, %1, %2" : "=v"(A1.u[1]) : "v"(e12v),"v"(e13));
        asm("v_cvt_pk_bf16_f32 %0, %1, %2" : "=v"(A1.u[2]) : "v"(e14), "v"(e15));
        asm("v_cvt_pk_bf16_f32 %0, %1, %2" : "=v"(A1.u[3]) : "v"(e16), "v"(e17));

        const int tile = j0 >> 5;
        const ushort* hb = hB + (size_t)(tile * 64 + lane) * 8;
        const bf16x8 b0 = *(const bf16x8*)(hb);
        const bf16x8 b1 = *(const bf16x8*)(hb + 256 * 64 * 8);
        const bf16x8 b2 = *(const bf16x8*)(hb + 2 * 256 * 64 * 8);
        const bf16x8 b3 = *(const bf16x8*)(hb + 3 * 256 * 64 * 8);

        a00 = __builtin_amdgcn_mfma_f32_16x16x32_bf16(A0.v, b0, a00, 0, 0, 0);
        a01 = __builtin_amdgcn_mfma_f32_16x16x32_bf16(A0.v, b1, a01, 0, 0, 0);
        a02 = __builtin_amdgcn_mfma_f32_16x16x32_bf16(A0.v, b2, a02, 0, 0, 0);
        a03 = __builtin_amdgcn_mfma_f32_16x16x32_bf16(A0.v, b3, a03, 0, 0, 0);
        a10 = __builtin_amdgcn_mfma_f32_16x16x32_bf16(A1.v, b0, a10, 0, 0, 0);
        a11 = __builtin_amdgcn_mfma_f32_16x16x32_bf16(A1.v, b1, a11, 0, 0, 0);
        a12 = __builtin_amdgcn_mfma_f32_16x16x32_bf16(A1.v, b2, a12, 0, 0, 0);
        a13 = __builtin_amdgcn_mfma_f32_16x16x32_bf16(A1.v, b3, a13, 0, 0, 0);
    }

    float* pout = part + (size_t)blockIdx.y * (NN * OUTF);
#pragma unroll
    for (int m = 0; m < 4; ++m) {
        const int row0 = ibase + g * 4 + m;
        const int row1 = ibase + 16 + g * 4 + m;
        pout[(size_t)row0 * OUTF + 0  + r] = a00[m];
        pout[(size_t)row0 * OUTF + 16 + r] = a01[m];
        pout[(size_t)row0 * OUTF + 32 + r] = a02[m];
        pout[(size_t)row0 * OUTF + 48 + r] = a03[m];
        pout[(size_t)row1 * OUTF + 0  + r] = a10[m];
        pout[(size_t)row1 * OUTF + 16 + r] = a11[m];
        pout[(size_t)row1 * OUTF + 32 + r] = a12[m];
        pout[(size_t)row1 * OUTF + 48 + r] = a13[m];
    }
}

// ---- Kernel 5: combine j-split partials + ELU (float4) ----
__global__ __launch_bounds__(256) void k5_combine(
    const float* __restrict__ part, float* __restrict__ out, int JS)
{
    const int base = (blockIdx.x * 256 + threadIdx.x) * 4;
    float4 v = make_float4(0.f, 0.f, 0.f, 0.f);
    for (int s = 0; s < JS; ++s) {
        const float4 p = *(const float4*)(part + (size_t)s * (NN * OUTF) + base);
        v.x += p.x; v.y += p.y; v.z += p.z; v.w += p.w;
    }
    float4 o;
    o.x = v.x > 0.f ? v.x : (__builtin_amdgcn_exp2f(v.x * LOG2E) - 1.f);
    o.y = v.y > 0.f ? v.y : (__builtin_amdgcn_exp2f(v.y * LOG2E) - 1.f);
    o.z = v.z > 0.f ? v.z : (__builtin_amdgcn_exp2f(v.z * LOG2E) - 1.f);
    o.w = v.w > 0.f ? v.w : (__builtin_amdgcn_exp2f(v.w * LOG2E) - 1.f);
    *(float4*)(out + base) = o;
}

extern "C" void kernel_launch(void* const* d_in, const int* in_sizes, int n_in,
                              void* d_out, int out_size, void* d_ws, size_t ws_size,
                              hipStream_t stream)
{
    const float* input  = (const float*)d_in[0];
    // d_in[1] = adj : unused by the reference computation
    const float* embeds = (const float*)d_in[2];
    const float* Wm     = (const float*)d_in[3];
    const float* av     = (const float*)d_in[4];
    const float* intw   = (const float*)d_in[5];
    // d_in[6] = intent_b : cancels in column softmax
    const float* betap  = (const float*)d_in[7];
    float* out = (float*)d_out;

    char* ws = (char*)d_ws;
    ushort* hB  = (ushort*)(ws + OFF_HB);
    float2* UW  = (float2*)(ws + OFF_UW);
    float2* e12 = (float2*)(ws + OFF_E12);
    float* S    = (float*)(ws + OFF_S);
    float* part = (float*)(ws + OFF_PART);

    int JS = 8;   // jch must be <= 2048 (LDS pq buffer)
    while (JS > 4 &&
           (size_t)OFF_PART + (size_t)JS * NN * OUTF * sizeof(float) > ws_size)
        JS >>= 1;
    const int jch = NN / JS;

    k1_h<<<NN / 16, 256, 0, stream>>>(input, Wm, av, embeds, intw, betap,
                                      hB, UW, e12, S);
    k2_colsum<<<dim3(NN / 512, ISPLIT), 256, 0, stream>>>(UW, e12, S);
    k4_mm<<<dim3(NN / 128, JS), 256, 0, stream>>>(UW, e12, S, hB, part, jch);
    k5_combine<<<(NN * OUTF) / 1024, 256, 0, stream>>>(part, out, JS);
}